// Round 3
// baseline (639.425 us; speedup 1.0000x reference)
//
#include <hip/hip_runtime.h>
#include <hip/hip_bf16.h>
#include <stdint.h>

#define B_   128
#define N_   196
#define E_   2048
#define D_   512
#define A_   512
#define MTOT (B_ * N_)   // 25088 = 392*64 exactly

typedef short  short8  __attribute__((ext_vector_type(8)));
typedef float  floatx4 __attribute__((ext_vector_type(4)));

__device__ __forceinline__ unsigned short f2bf(float f) {
    union { float f; uint32_t u; } v; v.f = f;
    uint32_t r = v.u + 0x7FFFu + ((v.u >> 16) & 1u);   // RNE
    return (unsigned short)(r >> 16);
}

// pack two fp32 -> two bf16 (round-half-up) in one dword: lo=bf16(a), hi=bf16(b)
__device__ __forceinline__ uint32_t pkbf(float a, float b) {
    uint32_t ua = __float_as_uint(a) + 0x8000u;
    uint32_t ub = __float_as_uint(b) + 0x8000u;
    return __builtin_amdgcn_perm(ub, ua, 0x07060302u);
}

// ---------------------------------------------------------------------------
// Kernel A2: We [2048][512] fp32 -> WeT [512][2048] bf16 (k-contiguous rows)
// ---------------------------------------------------------------------------
__global__ void transcvt_k(const float* __restrict__ We, unsigned short* __restrict__ WeT) {
    __shared__ float tile[32][33];
    const int e0 = blockIdx.x * 32, a0 = blockIdx.y * 32;
    const int t = threadIdx.x, tc = t & 31, tr = t >> 5;   // tr 0..7
#pragma unroll
    for (int i = 0; i < 4; ++i) {
        int r = tr + i * 8;
        tile[r][tc] = We[(size_t)(e0 + r) * A_ + a0 + tc];
    }
    __syncthreads();
#pragma unroll
    for (int i = 0; i < 4; ++i) {
        int r = tr + i * 8;
        WeT[(size_t)(a0 + r) * E_ + e0 + tc] = f2bf(tile[tc][r]);
    }
}

// ---------------------------------------------------------------------------
// Kernel A: att2p[b][a] = dh[b,:]@Wd[:,a] + bd[a] + be[a]   (fp32, tiny)
// ---------------------------------------------------------------------------
__launch_bounds__(512)
__global__ void att2_k(const float* __restrict__ dh, const float* __restrict__ Wd,
                       const float* __restrict__ bd, const float* __restrict__ be,
                       float* __restrict__ att2p) {
    const int b = blockIdx.x, t = threadIdx.x;
    __shared__ float sdh[D_];
    sdh[t] = dh[b * D_ + t];
    __syncthreads();
    float acc = 0.f;
#pragma unroll 8
    for (int d = 0; d < D_; ++d) acc += sdh[d] * Wd[(size_t)d * A_ + t];
    att2p[(size_t)b * A_ + t] = acc + bd[t] + be[t];
}

// ---------------------------------------------------------------------------
// Kernel B: fused bf16 MFMA GEMM (enc @ We) + tanh + dot(Wf) score epilogue.
// BARRIER-FREE K-loop: both operands stream global->register.
//   A frag: enc fp32, 2 float4/lane/tile, packed to bf16 in-register.
//   B frag: WeT bf16, 1 dwordx4/lane/tile (L2-resident, 2 MB).
// Register double-buffer, prefetch distance 2. No LDS in the K-loop.
// ---------------------------------------------------------------------------
__launch_bounds__(256, 2)
__global__ void score_gemm(const float* __restrict__ enc,
                           const unsigned short* __restrict__ WeT,
                           const float* __restrict__ att2p,
                           const float* __restrict__ Wf,
                           float* __restrict__ scoresP) {
    __shared__ float sPart[4][64];

    const int t   = threadIdx.x;
    const int w   = t >> 6;
    const int l   = t & 63;
    const int l15 = l & 15;
    const int q4  = l >> 4;
    const int row0  = blockIdx.y * 64;     // grid.y = 392
    const int cw0   = blockIdx.x * 256;    // grid.x = 2
    const int cbase = cw0 + w * 64;

    floatx4 acc[4][4] = {};

    // per-lane fragment base pointers (k advances by 32 elements per step)
    const float* pa[4];
    const unsigned short* pb[4];
#pragma unroll
    for (int mi = 0; mi < 4; ++mi)
        pa[mi] = enc + (size_t)(row0 + mi * 16 + l15) * E_ + q4 * 8;
#pragma unroll
    for (int ni = 0; ni < 4; ++ni)
        pb[ni] = WeT + (size_t)(cbase + ni * 16 + l15) * E_ + q4 * 8;

    float4 Afp[2][8];   // [stage][mi*2 + half]
    short8 Bst[2][4];   // [stage][ni]

#define LA(s, kk) do { int _ko = (kk) * 32;                                   \
        _Pragma("unroll")                                                     \
        for (int mi = 0; mi < 4; ++mi) {                                      \
            Afp[s][2*mi]   = *(const float4*)(pa[mi] + _ko);                  \
            Afp[s][2*mi+1] = *(const float4*)(pa[mi] + _ko + 4);              \
        } } while (0)
#define LB(s, kk) do { int _ko = (kk) * 32;                                   \
        _Pragma("unroll")                                                     \
        for (int ni = 0; ni < 4; ++ni)                                        \
            Bst[s][ni] = *(const short8*)(pb[ni] + _ko);                      \
        } while (0)

#define STEP(p, kk, PF) do {                                                  \
        union { uint32_t u[4]; short8 s; } afu[4];                            \
        _Pragma("unroll")                                                     \
        for (int mi = 0; mi < 4; ++mi) {                                      \
            float4 lo = Afp[p][2*mi], hi = Afp[p][2*mi+1];                    \
            afu[mi].u[0] = pkbf(lo.x, lo.y);                                  \
            afu[mi].u[1] = pkbf(lo.z, lo.w);                                  \
            afu[mi].u[2] = pkbf(hi.x, hi.y);                                  \
            afu[mi].u[3] = pkbf(hi.z, hi.w);                                  \
        }                                                                     \
        if (PF) LA(p, (kk) + 2);                                              \
        _Pragma("unroll")                                                     \
        for (int mi = 0; mi < 4; ++mi) {                                      \
            acc[mi][0] = __builtin_amdgcn_mfma_f32_16x16x32_bf16(afu[mi].s, Bst[p][0], acc[mi][0], 0, 0, 0); \
            acc[mi][1] = __builtin_amdgcn_mfma_f32_16x16x32_bf16(afu[mi].s, Bst[p][1], acc[mi][1], 0, 0, 0); \
            acc[mi][2] = __builtin_amdgcn_mfma_f32_16x16x32_bf16(afu[mi].s, Bst[p][2], acc[mi][2], 0, 0, 0); \
            acc[mi][3] = __builtin_amdgcn_mfma_f32_16x16x32_bf16(afu[mi].s, Bst[p][3], acc[mi][3], 0, 0, 0); \
        }                                                                     \
        if (PF) LB(p, (kk) + 2);                                              \
    } while (0)

    LA(0, 0); LB(0, 0);
    LA(1, 1); LB(1, 1);

    for (int kk = 0; kk < 62; kk += 2) {   // 64 K-steps of 32 total
        STEP(0, kk, true);
        STEP(1, kk + 1, true);
    }
    STEP(0, 62, false);
    STEP(1, 63, false);

#undef LA
#undef LB
#undef STEP

    // Epilogue: s[m] += sum_n tanh(acc + att2p[b(m),n]) * Wf[n]  (partial over 256 cols)
    float wfv[4];
#pragma unroll
    for (int ni = 0; ni < 4; ++ni) wfv[ni] = Wf[cbase + ni * 16 + l15];

#pragma unroll
    for (int mi = 0; mi < 4; ++mi) {
#pragma unroll
        for (int r = 0; r < 4; ++r) {
            const int m    = mi * 16 + q4 * 4 + r;     // D layout: row=(l>>4)*4+reg
            const int grow = row0 + m;
            const int bb   = grow / N_;
            const float* a2 = att2p + (size_t)bb * A_ + cbase;
            float s = 0.f;
#pragma unroll
            for (int ni = 0; ni < 4; ++ni) {
                float v  = acc[mi][ni][r] + a2[ni * 16 + l15];
                float e  = __expf(2.f * v);
                float th = 1.f - 2.f / (e + 1.f);      // tanh(v)
                s += th * wfv[ni];
            }
            s += __shfl_xor(s, 1);
            s += __shfl_xor(s, 2);
            s += __shfl_xor(s, 4);
            s += __shfl_xor(s, 8);
            if (l15 == 0) sPart[w][m] = s;
        }
    }
    __syncthreads();
    if (t < 64) {
        float v = sPart[0][t] + sPart[1][t] + sPart[2][t] + sPart[3][t];
        scoresP[(size_t)blockIdx.x * MTOT + row0 + t] = v;
    }
}

// ---------------------------------------------------------------------------
// Kernel C0: softmax over N=196 per batch (bf bias dropped — softmax-invariant)
// ---------------------------------------------------------------------------
__global__ void softmax_k(const float* __restrict__ sp, float* __restrict__ alpha) {
    const int b = blockIdx.x, t = threadIdx.x;
    const int w = t >> 6, l = t & 63;
    __shared__ float red[8];
    float v = -3.0e38f;
    if (t < N_) v = sp[b * N_ + t] + sp[MTOT + b * N_ + t];
    float m = v;
#pragma unroll
    for (int off = 32; off >= 1; off >>= 1) m = fmaxf(m, __shfl_xor(m, off));
    if (l == 0) red[w] = m;
    __syncthreads();
    m = fmaxf(fmaxf(red[0], red[1]), fmaxf(red[2], red[3]));
    float e = 0.f;
    if (t < N_) e = __expf(v - m);
    float s = e;
#pragma unroll
    for (int off = 32; off >= 1; off >>= 1) s += __shfl_xor(s, off);
    if (l == 0) red[4 + w] = s;
    __syncthreads();
    s = red[4] + red[5] + red[6] + red[7];
    if (t < N_) alpha[b * N_ + t] = e / s;
}

// ---------------------------------------------------------------------------
// Kernel C1: context[b, :] = sum_n alpha[b,n] * enc[b,n,:]   (fp32 stream)
// ---------------------------------------------------------------------------
__launch_bounds__(256)
__global__ void context_k(const float* __restrict__ enc, const float* __restrict__ alpha,
                          float* __restrict__ ctx) {
    const int chunk = blockIdx.x, b = blockIdx.y;
    const int t = threadIdx.x, tn = t >> 6, tc = t & 63;
    __shared__ float  sAl[N_];
    __shared__ float4 sRed[256];
    if (t < N_) sAl[t] = alpha[b * N_ + t];
    __syncthreads();
    const float* base = enc + (size_t)b * N_ * E_ + chunk * 256 + tc * 4;
    float4 a = make_float4(0.f, 0.f, 0.f, 0.f);
#pragma unroll 7
    for (int n = tn; n < N_; n += 4) {
        float  al = sAl[n];
        float4 v  = *(const float4*)(base + (size_t)n * E_);
        a.x += al * v.x; a.y += al * v.y; a.z += al * v.z; a.w += al * v.w;
    }
    sRed[t] = a;
    __syncthreads();
    if (t < 64) {
        float4 r0 = sRed[t], r1 = sRed[t + 64], r2 = sRed[t + 128], r3 = sRed[t + 192];
        float4 o = make_float4(r0.x + r1.x + r2.x + r3.x, r0.y + r1.y + r2.y + r3.y,
                               r0.z + r1.z + r2.z + r3.z, r0.w + r1.w + r2.w + r3.w);
        *(float4*)(ctx + (size_t)b * E_ + chunk * 256 + t * 4) = o;
    }
}

// ---------------------------------------------------------------------------
extern "C" void kernel_launch(void* const* d_in, const int* in_sizes, int n_in,
                              void* d_out, int out_size, void* d_ws, size_t ws_size,
                              hipStream_t stream) {
    const float* enc = (const float*)d_in[0];
    const float* dh  = (const float*)d_in[1];
    const float* We  = (const float*)d_in[2];
    const float* be  = (const float*)d_in[3];
    const float* Wd  = (const float*)d_in[4];
    const float* bd  = (const float*)d_in[5];
    const float* Wf  = (const float*)d_in[6];
    // d_in[7] = bf: additive constant on scores, cancels in softmax.

    float* out   = (float*)d_out;
    float* ctx   = out;              // [128, 2048]
    float* alpha = out + B_ * E_;    // [128, 196]

    char* ws = (char*)d_ws;
    unsigned short* WeT  = (unsigned short*)ws;                       // 2 MB
    float* att2p         = (float*)(ws + (2u << 20));                 // 256 KB
    float* scoresP       = (float*)(ws + (2u << 20) + (256u << 10));  // 2 x 25088 fp32

    transcvt_k <<<dim3(E_ / 32, A_ / 32), 256, 0, stream>>>(We, WeT);
    att2_k     <<<dim3(B_),              512, 0, stream>>>(dh, Wd, bd, be, att2p);
    score_gemm <<<dim3(2, MTOT / 64),    256, 0, stream>>>(enc, WeT, att2p, Wf, scoresP);
    softmax_k  <<<dim3(B_),              256, 0, stream>>>(scoresP, alpha);
    context_k  <<<dim3(E_ / 256, B_),    256, 0, stream>>>(enc, alpha, ctx);
}

// Round 4
// 495.592 us; speedup vs baseline: 1.2902x; 1.2902x over previous
//
#include <hip/hip_runtime.h>
#include <hip/hip_bf16.h>
#include <stdint.h>

#define B_   128
#define N_   196
#define E_   2048
#define D_   512
#define A_   512
#define MTOT (B_ * N_)   // 25088 = 196*128 exactly

typedef short  short8  __attribute__((ext_vector_type(8)));
typedef float  floatx4 __attribute__((ext_vector_type(4)));

__device__ __forceinline__ unsigned short f2bf(float f) {
    union { float f; uint32_t u; } v; v.f = f;
    uint32_t r = v.u + 0x7FFFu + ((v.u >> 16) & 1u);   // RNE
    return (unsigned short)(r >> 16);
}

// pack two fp32 -> two bf16 (round-half-up) in one dword: lo=bf16(a), hi=bf16(b)
__device__ __forceinline__ uint32_t pkbf(float a, float b) {
    uint32_t ua = __float_as_uint(a) + 0x8000u;
    uint32_t ub = __float_as_uint(b) + 0x8000u;
    return __builtin_amdgcn_perm(ub, ua, 0x07060302u);
}

// ---------------------------------------------------------------------------
// Kernel A2: We [2048][512] fp32 -> WeT [512][2048] bf16 (k-contiguous rows)
// ---------------------------------------------------------------------------
__global__ void transcvt_k(const float* __restrict__ We, unsigned short* __restrict__ WeT) {
    __shared__ float tile[32][33];
    const int e0 = blockIdx.x * 32, a0 = blockIdx.y * 32;
    const int t = threadIdx.x, tc = t & 31, tr = t >> 5;   // tr 0..7
#pragma unroll
    for (int i = 0; i < 4; ++i) {
        int r = tr + i * 8;
        tile[r][tc] = We[(size_t)(e0 + r) * A_ + a0 + tc];
    }
    __syncthreads();
#pragma unroll
    for (int i = 0; i < 4; ++i) {
        int r = tr + i * 8;
        WeT[(size_t)(a0 + r) * E_ + e0 + tc] = f2bf(tile[tc][r]);
    }
}

// ---------------------------------------------------------------------------
// Kernel A: att2p[b][a] = dh[b,:]@Wd[:,a] + bd[a] + be[a]   (fp32, tiny)
// ---------------------------------------------------------------------------
__launch_bounds__(512)
__global__ void att2_k(const float* __restrict__ dh, const float* __restrict__ Wd,
                       const float* __restrict__ bd, const float* __restrict__ be,
                       float* __restrict__ att2p) {
    const int b = blockIdx.x, t = threadIdx.x;
    __shared__ float sdh[D_];
    sdh[t] = dh[b * D_ + t];
    __syncthreads();
    float acc = 0.f;
#pragma unroll 8
    for (int d = 0; d < D_; ++d) acc += sdh[d] * Wd[(size_t)d * A_ + t];
    att2p[(size_t)b * A_ + t] = acc + bd[t] + be[t];
}

// ---------------------------------------------------------------------------
// Kernel B: fused bf16 MFMA GEMM (enc @ We) + tanh + dot(Wf) score epilogue.
// m97 structure: 128x128 tile, BK=32, single-buffer LDS, 2 barriers/iter,
// BOTH operands staged via global_load_lds (A raw fp32 16KB, B bf16 8KB).
// fp32->bf16 pack happens in the LDS->reg phase. XOR swizzle keeps DMA
// lane-linear AND ds_read_b128 at free 2-way aliasing.
// ---------------------------------------------------------------------------
__launch_bounds__(256, 3)
__global__ void score_gemm(const float* __restrict__ enc,
                           const unsigned short* __restrict__ WeT,
                           const float* __restrict__ att2p,
                           const float* __restrict__ Wf,
                           float* __restrict__ scoresP) {
    // sA: 128 rows x 32 k fp32, row-major, phys chunk p = c ^ (r&7)   (16 KB)
    // sB: 128 cols x 32 k bf16, phys chunk p = c ^ ((n>>2)&3)         ( 8 KB)
    __shared__ __align__(16) char sMem[16384 + 8192];
    __shared__ float sPart[4][64];

    const int t   = threadIdx.x;
    const int w   = t >> 6;
    const int l   = t & 63;
    const int l15 = l & 15;
    const int q4  = l >> 4;
    const int wm  = w >> 1;               // row half (0/1)
    const int wn  = w & 1;                // col half (0/1)
    const int row0 = blockIdx.y * 128;    // grid.y = 196
    const int col0 = blockIdx.x * 128;    // grid.x = 4

    floatx4 acc[4][4] = {};

    // ---- A DMA: 16 wave-insts (4/wave). slot s = w*256+j*64+l -> r=s>>3, p=s&7
    const float* aSrc[4];
    int aDst[4];
#pragma unroll
    for (int j = 0; j < 4; ++j) {
        int s  = w * 256 + j * 64 + l;
        int r  = s >> 3, p = s & 7;
        int cs = p ^ (r & 7);
        aSrc[j] = enc + (size_t)(row0 + r) * E_ + cs * 4;
        aDst[j] = (w * 256 + j * 64) * 16;          // wave-uniform byte base
    }
    // ---- B DMA: 8 wave-insts (2/wave). slot s = w*128+j*64+l -> n=s>>2, p=s&3
    const unsigned short* bSrc[2];
    int bDst[2];
#pragma unroll
    for (int j = 0; j < 2; ++j) {
        int s  = w * 128 + j * 64 + l;
        int n  = s >> 2, p = s & 3;
        int cs = p ^ ((n >> 2) & 3);
        bSrc[j] = WeT + (size_t)(col0 + n) * E_ + cs * 8;
        bDst[j] = 16384 + (w * 128 + j * 64) * 16;  // wave-uniform byte base
    }

    // ---- frag read offsets
    const int p0 = (2 * q4) ^ (l15 & 7);            // A phys chunk of first half
    int offA[4], offA2[4], offB[4];
#pragma unroll
    for (int mi = 0; mi < 4; ++mi) {
        int rA  = wm * 64 + mi * 16 + l15;
        offA[mi]  = rA * 128 + p0 * 16;
        offA2[mi] = rA * 128 + (p0 ^ 1) * 16;
    }
#pragma unroll
    for (int ni = 0; ni < 4; ++ni) {
        int nB = wn * 64 + ni * 16 + l15;
        offB[ni] = 16384 + nB * 64 + (q4 ^ ((l15 >> 2) & 3)) * 16;
    }

    for (int kk = 0; kk < 64; ++kk) {
#pragma unroll
        for (int j = 0; j < 4; ++j)
            __builtin_amdgcn_global_load_lds(
                (const __attribute__((address_space(1))) uint32_t*)(aSrc[j] + kk * 32),
                (__attribute__((address_space(3))) uint32_t*)(sMem + aDst[j]), 16, 0, 0);
#pragma unroll
        for (int j = 0; j < 2; ++j)
            __builtin_amdgcn_global_load_lds(
                (const __attribute__((address_space(1))) uint32_t*)(bSrc[j] + kk * 32),
                (__attribute__((address_space(3))) uint32_t*)(sMem + bDst[j]), 16, 0, 0);
        __syncthreads();

        short8 bfr[4];
        union { uint32_t u[4]; short8 s; } af[4];
#pragma unroll
        for (int ni = 0; ni < 4; ++ni)
            bfr[ni] = *(const short8*)(sMem + offB[ni]);
#pragma unroll
        for (int mi = 0; mi < 4; ++mi) {
            float4 lo = *(const float4*)(sMem + offA[mi]);    // k = q4*8 .. +3
            float4 hi = *(const float4*)(sMem + offA2[mi]);   // k = q4*8+4 .. +7
            af[mi].u[0] = pkbf(lo.x, lo.y);
            af[mi].u[1] = pkbf(lo.z, lo.w);
            af[mi].u[2] = pkbf(hi.x, hi.y);
            af[mi].u[3] = pkbf(hi.z, hi.w);
        }
#pragma unroll
        for (int mi = 0; mi < 4; ++mi) {
            acc[mi][0] = __builtin_amdgcn_mfma_f32_16x16x32_bf16(af[mi].s, bfr[0], acc[mi][0], 0, 0, 0);
            acc[mi][1] = __builtin_amdgcn_mfma_f32_16x16x32_bf16(af[mi].s, bfr[1], acc[mi][1], 0, 0, 0);
            acc[mi][2] = __builtin_amdgcn_mfma_f32_16x16x32_bf16(af[mi].s, bfr[2], acc[mi][2], 0, 0, 0);
            acc[mi][3] = __builtin_amdgcn_mfma_f32_16x16x32_bf16(af[mi].s, bfr[3], acc[mi][3], 0, 0, 0);
        }
        __syncthreads();
    }

    // Epilogue: s[m] += sum_n tanh(acc + att2p[b(m),n]) * Wf[n]  (partial, 128 cols)
    const int cbase = col0 + wn * 64;
    float wfv[4];
#pragma unroll
    for (int ni = 0; ni < 4; ++ni) wfv[ni] = Wf[cbase + ni * 16 + l15];

#pragma unroll
    for (int mi = 0; mi < 4; ++mi) {
#pragma unroll
        for (int r = 0; r < 4; ++r) {
            const int m    = mi * 16 + q4 * 4 + r;          // row within 64-half
            const int grow = row0 + wm * 64 + m;
            const int bb   = grow / N_;
            const float* a2 = att2p + (size_t)bb * A_ + cbase;
            float s = 0.f;
#pragma unroll
            for (int ni = 0; ni < 4; ++ni) {
                float v  = acc[mi][ni][r] + a2[ni * 16 + l15];
                float e  = __expf(2.f * v);
                float th = 1.f - 2.f / (e + 1.f);           // tanh(v)
                s += th * wfv[ni];
            }
            s += __shfl_xor(s, 1);
            s += __shfl_xor(s, 2);
            s += __shfl_xor(s, 4);
            s += __shfl_xor(s, 8);
            if (l15 == 0) sPart[w][m] = s;
        }
    }
    __syncthreads();
    if (t < 128) {
        const int h = t >> 6, m = t & 63;
        float v = sPart[h * 2 + 0][m] + sPart[h * 2 + 1][m];
        scoresP[(size_t)blockIdx.x * MTOT + row0 + t] = v;
    }
}

// ---------------------------------------------------------------------------
// Kernel C0: softmax over N=196 per batch (sums 4 col-tile partials)
// ---------------------------------------------------------------------------
__global__ void softmax_k(const float* __restrict__ sp, float* __restrict__ alpha) {
    const int b = blockIdx.x, t = threadIdx.x;
    const int w = t >> 6, l = t & 63;
    __shared__ float red[8];
    float v = -3.0e38f;
    if (t < N_) v = sp[b * N_ + t] + sp[MTOT + b * N_ + t]
                  + sp[2 * MTOT + b * N_ + t] + sp[3 * MTOT + b * N_ + t];
    float m = v;
#pragma unroll
    for (int off = 32; off >= 1; off >>= 1) m = fmaxf(m, __shfl_xor(m, off));
    if (l == 0) red[w] = m;
    __syncthreads();
    m = fmaxf(fmaxf(red[0], red[1]), fmaxf(red[2], red[3]));
    float e = 0.f;
    if (t < N_) e = __expf(v - m);
    float s = e;
#pragma unroll
    for (int off = 32; off >= 1; off >>= 1) s += __shfl_xor(s, off);
    if (l == 0) red[4 + w] = s;
    __syncthreads();
    s = red[4] + red[5] + red[6] + red[7];
    if (t < N_) alpha[b * N_ + t] = e / s;
}

// ---------------------------------------------------------------------------
// Kernel C1: context[b, :] = sum_n alpha[b,n] * enc[b,n,:]   (fp32 stream)
// ---------------------------------------------------------------------------
__launch_bounds__(256)
__global__ void context_k(const float* __restrict__ enc, const float* __restrict__ alpha,
                          float* __restrict__ ctx) {
    const int chunk = blockIdx.x, b = blockIdx.y;
    const int t = threadIdx.x, tn = t >> 6, tc = t & 63;
    __shared__ float  sAl[N_];
    __shared__ float4 sRed[256];
    if (t < N_) sAl[t] = alpha[b * N_ + t];
    __syncthreads();
    const float* base = enc + (size_t)b * N_ * E_ + chunk * 256 + tc * 4;
    float4 a = make_float4(0.f, 0.f, 0.f, 0.f);
#pragma unroll 7
    for (int n = tn; n < N_; n += 4) {
        float  al = sAl[n];
        float4 v  = *(const float4*)(base + (size_t)n * E_);
        a.x += al * v.x; a.y += al * v.y; a.z += al * v.z; a.w += al * v.w;
    }
    sRed[t] = a;
    __syncthreads();
    if (t < 64) {
        float4 r0 = sRed[t], r1 = sRed[t + 64], r2 = sRed[t + 128], r3 = sRed[t + 192];
        float4 o = make_float4(r0.x + r1.x + r2.x + r3.x, r0.y + r1.y + r2.y + r3.y,
                               r0.z + r1.z + r2.z + r3.z, r0.w + r1.w + r2.w + r3.w);
        *(float4*)(ctx + (size_t)b * E_ + chunk * 256 + t * 4) = o;
    }
}

// ---------------------------------------------------------------------------
extern "C" void kernel_launch(void* const* d_in, const int* in_sizes, int n_in,
                              void* d_out, int out_size, void* d_ws, size_t ws_size,
                              hipStream_t stream) {
    const float* enc = (const float*)d_in[0];
    const float* dh  = (const float*)d_in[1];
    const float* We  = (const float*)d_in[2];
    const float* be  = (const float*)d_in[3];
    const float* Wd  = (const float*)d_in[4];
    const float* bd  = (const float*)d_in[5];
    const float* Wf  = (const float*)d_in[6];
    // d_in[7] = bf: additive constant on scores, cancels in softmax.

    float* out   = (float*)d_out;
    float* ctx   = out;              // [128, 2048]
    float* alpha = out + B_ * E_;    // [128, 196]

    char* ws = (char*)d_ws;
    unsigned short* WeT  = (unsigned short*)ws;                       // 2 MB
    float* att2p         = (float*)(ws + (2u << 20));                 // 256 KB
    float* scoresP       = (float*)(ws + (2u << 20) + (256u << 10));  // 4 x 25088 fp32

    transcvt_k <<<dim3(E_ / 32, A_ / 32), 256, 0, stream>>>(We, WeT);
    att2_k     <<<dim3(B_),              512, 0, stream>>>(dh, Wd, bd, be, att2p);
    score_gemm <<<dim3(4, MTOT / 128),   256, 0, stream>>>(enc, WeT, att2p, Wf, scoresP);
    softmax_k  <<<dim3(B_),              256, 0, stream>>>(scoresP, alpha);
    context_k  <<<dim3(E_ / 256, B_),    256, 0, stream>>>(enc, alpha, ctx);
}

// Round 5
// 439.986 us; speedup vs baseline: 1.4533x; 1.1264x over previous
//
#include <hip/hip_runtime.h>
#include <hip/hip_bf16.h>
#include <stdint.h>

#define B_   128
#define N_   196
#define E_   2048
#define D_   512
#define A_   512
#define MTOT (B_ * N_)   // 25088 = 392*64 exactly

typedef short  short8  __attribute__((ext_vector_type(8)));
typedef float  floatx4 __attribute__((ext_vector_type(4)));

__device__ __forceinline__ unsigned short f2bf(float f) {
    union { float f; uint32_t u; } v; v.f = f;
    uint32_t r = v.u + 0x7FFFu + ((v.u >> 16) & 1u);   // RNE
    return (unsigned short)(r >> 16);
}

// pack two fp32 -> two bf16 (round-half-up) in one dword: lo=bf16(a), hi=bf16(b)
__device__ __forceinline__ uint32_t pkbf(float a, float b) {
    uint32_t ua = __float_as_uint(a) + 0x8000u;
    uint32_t ub = __float_as_uint(b) + 0x8000u;
    return __builtin_amdgcn_perm(ub, ua, 0x07060302u);
}

// ---------------------------------------------------------------------------
// Kernel A2: We [2048][512] fp32 -> WeT [512][2048] bf16 (k-contiguous rows)
// ---------------------------------------------------------------------------
__global__ void transcvt_k(const float* __restrict__ We, unsigned short* __restrict__ WeT) {
    __shared__ float tile[32][33];
    const int e0 = blockIdx.x * 32, a0 = blockIdx.y * 32;
    const int t = threadIdx.x, tc = t & 31, tr = t >> 5;   // tr 0..7
#pragma unroll
    for (int i = 0; i < 4; ++i) {
        int r = tr + i * 8;
        tile[r][tc] = We[(size_t)(e0 + r) * A_ + a0 + tc];
    }
    __syncthreads();
#pragma unroll
    for (int i = 0; i < 4; ++i) {
        int r = tr + i * 8;
        WeT[(size_t)(a0 + r) * E_ + e0 + tc] = f2bf(tile[tc][r]);
    }
}

// ---------------------------------------------------------------------------
// Kernel A: att2p[b][a] = dh[b,:]@Wd[:,a] + bd[a] + be[a]   (fp32, tiny)
// ---------------------------------------------------------------------------
__launch_bounds__(512)
__global__ void att2_k(const float* __restrict__ dh, const float* __restrict__ Wd,
                       const float* __restrict__ bd, const float* __restrict__ be,
                       float* __restrict__ att2p) {
    const int b = blockIdx.x, t = threadIdx.x;
    __shared__ float sdh[D_];
    sdh[t] = dh[b * D_ + t];
    __syncthreads();
    float acc = 0.f;
#pragma unroll 8
    for (int d = 0; d < D_; ++d) acc += sdh[d] * Wd[(size_t)d * A_ + t];
    att2p[(size_t)b * A_ + t] = acc + bd[t] + be[t];
}

// ---------------------------------------------------------------------------
// Kernel B: fused bf16 MFMA GEMM (enc @ We) + tanh + dot(Wf) score epilogue.
// ONE block per 64-row strip covers ALL 512 columns -> enc read from HBM
// exactly once (205 MB), WeT (2 MB) streams from L2.
// 512 threads = 8 waves; wave w owns cols w*64..+63 (acc 4x4 = 64 VGPRs).
// m97 staging: global_load_lds for A (fp32, 8 KB) and B (bf16, 32 KB),
// BK=32, single buffer, 2 barriers/iter. fp32->bf16 pack after LDS read.
// ---------------------------------------------------------------------------
__launch_bounds__(512, 4)
__global__ void score_gemm(const float* __restrict__ enc,
                           const unsigned short* __restrict__ WeT,
                           const float* __restrict__ att2p,
                           const float* __restrict__ Wf,
                           float* __restrict__ scoresP) {
    // sA: 64 rows x 32 k fp32 (128 B/row), phys 16B-chunk p = lc ^ (r&7)  (8 KB)
    // sB: 512 cols x 32 k bf16 (64 B/row), phys 16B-quarter p = q ^ ((n>>1)&3) (32 KB)
    __shared__ __align__(16) char sMem[8192 + 32768];
    __shared__ float sPart[8][64];

    const int t   = threadIdx.x;
    const int w   = t >> 6;               // 0..7
    const int l   = t & 63;
    const int l15 = l & 15;
    const int q4  = l >> 4;
    const int row0 = blockIdx.x * 64;     // grid = 392

    floatx4 acc[4][4] = {};

    // ---- A DMA: 8 wave-insts (1/wave). slot s = w*64+l -> r=s>>3, p=s&7
    const float* aSrc;
    int aDst;
    {
        int s = w * 64 + l;
        int r = s >> 3, p = s & 7;
        aSrc = enc + (size_t)(row0 + r) * E_ + ((p ^ (r & 7)) * 4);
        aDst = w * 1024;                  // wave-uniform byte base
    }
    // ---- B DMA: 32 wave-insts (4/wave). slot s = (w*4+j)*64+l -> n=s>>2, p=s&3
    const unsigned short* bSrc[4];
    int bDst[4];
#pragma unroll
    for (int j = 0; j < 4; ++j) {
        int s = (w * 4 + j) * 64 + l;
        int n = s >> 2, p = s & 3;
        int q = p ^ ((n >> 1) & 3);
        bSrc[j] = WeT + (size_t)n * E_ + q * 8;
        bDst[j] = 8192 + (w * 4 + j) * 1024;
    }

    // ---- LDS read offsets
    const int pLo   = (2 * q4) ^ (l15 & 7);
    const int offAlo = l15 * 128 + pLo * 16;          // + mi*2048
    const int offAhi = l15 * 128 + (pLo ^ 1) * 16;
    const int offB   = 8192 + (w * 64 + l15) * 64 + (q4 ^ ((l15 >> 1) & 3)) * 16; // + ni*1024

    for (int kk = 0; kk < 64; ++kk) {
        __builtin_amdgcn_global_load_lds(
            (const __attribute__((address_space(1))) uint32_t*)(aSrc + kk * 32),
            (__attribute__((address_space(3))) uint32_t*)(sMem + aDst), 16, 0, 0);
#pragma unroll
        for (int j = 0; j < 4; ++j)
            __builtin_amdgcn_global_load_lds(
                (const __attribute__((address_space(1))) uint32_t*)(bSrc[j] + kk * 32),
                (__attribute__((address_space(3))) uint32_t*)(sMem + bDst[j]), 16, 0, 0);
        __syncthreads();

        short8 bfr[4];
        union { uint32_t u[4]; short8 s; } af[4];
#pragma unroll
        for (int ni = 0; ni < 4; ++ni)
            bfr[ni] = *(const short8*)(sMem + offB + ni * 1024);
#pragma unroll
        for (int mi = 0; mi < 4; ++mi) {
            float4 lo = *(const float4*)(sMem + offAlo + mi * 2048);  // k q4*8..+3
            float4 hi = *(const float4*)(sMem + offAhi + mi * 2048);  // k q4*8+4..+7
            af[mi].u[0] = pkbf(lo.x, lo.y);
            af[mi].u[1] = pkbf(lo.z, lo.w);
            af[mi].u[2] = pkbf(hi.x, hi.y);
            af[mi].u[3] = pkbf(hi.z, hi.w);
        }
#pragma unroll
        for (int mi = 0; mi < 4; ++mi) {
            acc[mi][0] = __builtin_amdgcn_mfma_f32_16x16x32_bf16(af[mi].s, bfr[0], acc[mi][0], 0, 0, 0);
            acc[mi][1] = __builtin_amdgcn_mfma_f32_16x16x32_bf16(af[mi].s, bfr[1], acc[mi][1], 0, 0, 0);
            acc[mi][2] = __builtin_amdgcn_mfma_f32_16x16x32_bf16(af[mi].s, bfr[2], acc[mi][2], 0, 0, 0);
            acc[mi][3] = __builtin_amdgcn_mfma_f32_16x16x32_bf16(af[mi].s, bfr[3], acc[mi][3], 0, 0, 0);
        }
        __syncthreads();
    }

    // Epilogue: s[m] = sum over ALL 512 cols of tanh(acc + att2p)*Wf -> complete score
    const int cbase = w * 64;
    float wfv[4];
#pragma unroll
    for (int ni = 0; ni < 4; ++ni) wfv[ni] = Wf[cbase + ni * 16 + l15];

#pragma unroll
    for (int mi = 0; mi < 4; ++mi) {
#pragma unroll
        for (int r = 0; r < 4; ++r) {
            const int m    = mi * 16 + q4 * 4 + r;     // D layout: row=(l>>4)*4+reg
            const int grow = row0 + m;
            const int bb   = grow / N_;
            const float* a2 = att2p + (size_t)bb * A_ + cbase;
            float s = 0.f;
#pragma unroll
            for (int ni = 0; ni < 4; ++ni) {
                float v  = acc[mi][ni][r] + a2[ni * 16 + l15];
                float e  = __expf(2.f * v);
                float th = 1.f - 2.f / (e + 1.f);      // tanh(v)
                s += th * wfv[ni];
            }
            s += __shfl_xor(s, 1);
            s += __shfl_xor(s, 2);
            s += __shfl_xor(s, 4);
            s += __shfl_xor(s, 8);
            if (l15 == 0) sPart[w][m] = s;
        }
    }
    __syncthreads();
    if (t < 64) {
        float v = 0.f;
#pragma unroll
        for (int ww = 0; ww < 8; ++ww) v += sPart[ww][t];
        scoresP[row0 + t] = v;
    }
}

// ---------------------------------------------------------------------------
// Kernel C0: softmax over N=196 per batch (bf bias dropped — softmax-invariant)
// ---------------------------------------------------------------------------
__global__ void softmax_k(const float* __restrict__ sp, float* __restrict__ alpha) {
    const int b = blockIdx.x, t = threadIdx.x;
    const int w = t >> 6, l = t & 63;
    __shared__ float red[8];
    float v = -3.0e38f;
    if (t < N_) v = sp[b * N_ + t];
    float m = v;
#pragma unroll
    for (int off = 32; off >= 1; off >>= 1) m = fmaxf(m, __shfl_xor(m, off));
    if (l == 0) red[w] = m;
    __syncthreads();
    m = fmaxf(fmaxf(red[0], red[1]), fmaxf(red[2], red[3]));
    float e = 0.f;
    if (t < N_) e = __expf(v - m);
    float s = e;
#pragma unroll
    for (int off = 32; off >= 1; off >>= 1) s += __shfl_xor(s, off);
    if (l == 0) red[4 + w] = s;
    __syncthreads();
    s = red[4] + red[5] + red[6] + red[7];
    if (t < N_) alpha[b * N_ + t] = e / s;
}

// ---------------------------------------------------------------------------
// Kernel C1: context[b, :] = sum_n alpha[b,n] * enc[b,n,:]   (fp32 stream)
// ---------------------------------------------------------------------------
__launch_bounds__(256)
__global__ void context_k(const float* __restrict__ enc, const float* __restrict__ alpha,
                          float* __restrict__ ctx) {
    const int chunk = blockIdx.x, b = blockIdx.y;
    const int t = threadIdx.x, tn = t >> 6, tc = t & 63;
    __shared__ float  sAl[N_];
    __shared__ float4 sRed[256];
    if (t < N_) sAl[t] = alpha[b * N_ + t];
    __syncthreads();
    const float* base = enc + (size_t)b * N_ * E_ + chunk * 256 + tc * 4;
    float4 a = make_float4(0.f, 0.f, 0.f, 0.f);
#pragma unroll 7
    for (int n = tn; n < N_; n += 4) {
        float  al = sAl[n];
        float4 v  = *(const float4*)(base + (size_t)n * E_);
        a.x += al * v.x; a.y += al * v.y; a.z += al * v.z; a.w += al * v.w;
    }
    sRed[t] = a;
    __syncthreads();
    if (t < 64) {
        float4 r0 = sRed[t], r1 = sRed[t + 64], r2 = sRed[t + 128], r3 = sRed[t + 192];
        float4 o = make_float4(r0.x + r1.x + r2.x + r3.x, r0.y + r1.y + r2.y + r3.y,
                               r0.z + r1.z + r2.z + r3.z, r0.w + r1.w + r2.w + r3.w);
        *(float4*)(ctx + (size_t)b * E_ + chunk * 256 + t * 4) = o;
    }
}

// ---------------------------------------------------------------------------
extern "C" void kernel_launch(void* const* d_in, const int* in_sizes, int n_in,
                              void* d_out, int out_size, void* d_ws, size_t ws_size,
                              hipStream_t stream) {
    const float* enc = (const float*)d_in[0];
    const float* dh  = (const float*)d_in[1];
    const float* We  = (const float*)d_in[2];
    const float* be  = (const float*)d_in[3];
    const float* Wd  = (const float*)d_in[4];
    const float* bd  = (const float*)d_in[5];
    const float* Wf  = (const float*)d_in[6];
    // d_in[7] = bf: additive constant on scores, cancels in softmax.

    float* out   = (float*)d_out;
    float* ctx   = out;              // [128, 2048]
    float* alpha = out + B_ * E_;    // [128, 196]

    char* ws = (char*)d_ws;
    unsigned short* WeT  = (unsigned short*)ws;                       // 2 MB
    float* att2p         = (float*)(ws + (2u << 20));                 // 256 KB
    float* scoresP       = (float*)(ws + (2u << 20) + (256u << 10));  // 25088 fp32

    transcvt_k <<<dim3(E_ / 32, A_ / 32), 256, 0, stream>>>(We, WeT);
    att2_k     <<<dim3(B_),              512, 0, stream>>>(dh, Wd, bd, be, att2p);
    score_gemm <<<dim3(MTOT / 64),       512, 0, stream>>>(enc, WeT, att2p, Wf, scoresP);
    softmax_k  <<<dim3(B_),              256, 0, stream>>>(scoresP, alpha);
    context_k  <<<dim3(E_ / 256, B_),    256, 0, stream>>>(enc, alpha, ctx);
}